// Round 1
// baseline (543.950 us; speedup 1.0000x reference)
//
#include <hip/hip_runtime.h>
#include <hip/hip_bf16.h>
#include <cstdint>
#include <cstddef>

#define DEVINL __device__ __forceinline__

typedef float f32x4 __attribute__((ext_vector_type(4)));
typedef short s16x8 __attribute__((ext_vector_type(8)));
typedef short s16x4 __attribute__((ext_vector_type(4)));

static constexpr int Sd = 2048;   // sequence
static constexpr int Hd = 1024;   // hidden
static constexpr int NHd = 16;    // heads
static constexpr int Dd = 64;     // head dim
static constexpr int N3 = 3072;   // 3*H

DEVINL float bf2f(short u){
  unsigned int t = ((unsigned int)(unsigned short)u) << 16;
  float f; __builtin_memcpy(&f, &t, 4); return f;
}
DEVINL short f2bf(float f){
  unsigned int t; __builtin_memcpy(&t, &f, 4);
  unsigned int r = t + 0x7FFFu + ((t >> 16) & 1u);   // RNE
  return (short)(r >> 16);
}

DEVINL void gld16(const short* g, short* l){
  __builtin_amdgcn_global_load_lds((const __attribute__((address_space(1))) unsigned int*)g,
                                   (__attribute__((address_space(3))) unsigned int*)l, 16, 0, 0);
}

// ---------------- LayerNorm + cast to bf16 ----------------
__global__ __launch_bounds__(256) void ln_kernel(const float* __restrict__ x,
                                                 const float* __restrict__ w,
                                                 const float* __restrict__ bs,
                                                 short* __restrict__ h){
  int row = blockIdx.x, tid = threadIdx.x;          // 8192 rows, 4 f32/thread
  const float* xr = x + (size_t)row * Hd;
  f32x4 v = *(const f32x4*)(xr + tid*4);
  float s1 = v[0]+v[1]+v[2]+v[3];
  float s2 = v[0]*v[0]+v[1]*v[1]+v[2]*v[2]+v[3]*v[3];
  #pragma unroll
  for (int off = 1; off < 64; off <<= 1){ s1 += __shfl_xor(s1, off); s2 += __shfl_xor(s2, off); }
  __shared__ float red[8];
  if ((tid & 63) == 0){ red[(tid>>6)*2] = s1; red[(tid>>6)*2+1] = s2; }
  __syncthreads();
  s1 = red[0]+red[2]+red[4]+red[6];
  s2 = red[1]+red[3]+red[5]+red[7];
  float mu = s1 * (1.0f/Hd);
  float rstd = rsqrtf(s2*(1.0f/Hd) - mu*mu + 1e-12f);
  f32x4 wv = *(const f32x4*)(w + tid*4);
  f32x4 bv = *(const f32x4*)(bs + tid*4);
  s16x4 o;
  #pragma unroll
  for (int i=0;i<4;i++) o[i] = f2bf((v[i]-mu)*rstd*wv[i] + bv[i]);
  *(s16x4*)(h + (size_t)row*Hd + tid*4) = o;
}

// ---------------- W cast + transpose: [K=1024][N=3072] f32 -> [N][K] bf16 ----------------
__global__ __launch_bounds__(256) void castw_kernel(const float* __restrict__ w, short* __restrict__ wT){
  __shared__ float t[32][33];
  int n0 = blockIdx.x*32, k0 = blockIdx.y*32;
  int tx = threadIdx.x, ty = threadIdx.y;           // (32,8)
  #pragma unroll
  for (int i=0;i<4;i++) t[ty + i*8][tx] = w[(size_t)(k0 + ty + i*8)*N3 + n0 + tx];
  __syncthreads();
  #pragma unroll
  for (int i=0;i<4;i++) wT[(size_t)(n0 + ty + i*8)*Hd + k0 + tx] = f2bf(t[tx][ty + i*8]);
}

// ---------------- QKV GEMM: C[8192][3072] = h @ w + b, write q/k/v bf16 head-layout ----------------
__global__ __launch_bounds__(256) void gemm_kernel(const short* __restrict__ A,
                                                   const short* __restrict__ Bt,
                                                   const float* __restrict__ bias,
                                                   short* __restrict__ qo,
                                                   short* __restrict__ ko,
                                                   short* __restrict__ vo){
  __shared__ short lA[128*32];
  __shared__ short lB[128*32];
  int bid = blockIdx.x;
  // XCD-aware 2D chunk: each XCD owns 8 m-tiles x all 24 n-tiles (A panels stay L2-resident)
  int xcd = bid & 7, idx = bid >> 3;                 // idx 0..191
  int mt = xcd*8 + (idx & 7), nt = idx >> 3;         // mt 0..63, nt 0..23
  int m0 = mt*128, n0 = nt*128;
  int tid = threadIdx.x, lane = tid & 63, wv = tid >> 6;
  int l15 = lane & 15, lq = lane >> 4;
  int wr = wv >> 1, wc = wv & 1;
  f32x4 zero = {0.f,0.f,0.f,0.f};
  f32x4 acc[4][4];
  #pragma unroll
  for (int m=0;m<4;m++)
    #pragma unroll
    for (int n=0;n<4;n++) acc[m][n] = zero;
  int flat = tid*8;
  int row0 = flat >> 5, col0 = flat & 31;
  const short* ga = A  + (size_t)(m0 + row0)*Hd + col0;
  const short* gb = Bt + (size_t)(n0 + row0)*Hd + col0;
  short* lAw = lA + wv*512;
  short* lBw = lB + wv*512;
  for (int kk = 0; kk < Hd; kk += 32){
    __syncthreads();
    gld16(ga + kk,                 lAw);
    gld16(ga + kk + (size_t)64*Hd, lAw + 2048);
    gld16(gb + kk,                 lBw);
    gld16(gb + kk + (size_t)64*Hd, lBw + 2048);
    __syncthreads();
    s16x8 af[4], bf[4];
    #pragma unroll
    for (int m=0;m<4;m++) af[m] = *(const s16x8*)(lA + (wr*64 + m*16 + l15)*32 + 8*lq);
    #pragma unroll
    for (int n=0;n<4;n++) bf[n] = *(const s16x8*)(lB + (wc*64 + n*16 + l15)*32 + 8*lq);
    #pragma unroll
    for (int m=0;m<4;m++)
      #pragma unroll
      for (int n=0;n<4;n++)
        acc[m][n] = __builtin_amdgcn_mfma_f32_16x16x32_bf16(af[m], bf[n], acc[m][n], 0, 0, 0);
  }
  // epilogue: bias + scatter to [bh][S][D] bf16
  #pragma unroll
  for (int n=0;n<4;n++){
    int c = n0 + wc*64 + n*16 + l15;
    float bv = bias[c];
    int part = c >> 10, hh = (c >> 6) & 15, d = c & 63;
    short* dst = part == 0 ? qo : (part == 1 ? ko : vo);
    #pragma unroll
    for (int m=0;m<4;m++){
      #pragma unroll
      for (int j=0;j<4;j++){
        int r = m0 + wr*64 + m*16 + lq*4 + j;       // global row = b*2048 + s
        int b = r >> 11, s = r & 2047;
        dst[(((size_t)((b*NHd + hh)*Sd + s)) << 6) + d] = f2bf(acc[m][n][j] + bv);
      }
    }
  }
}

// ---------------- RoPE in-place on q,k; folds 0.125*log2(e) into q ----------------
__global__ __launch_bounds__(256) void rope_kernel(short* __restrict__ q, short* __restrict__ k,
                                                   const float* __restrict__ sp){
  unsigned int idx = blockIdx.x*256 + threadIdx.x;  // 2^20 threads
  int part = idx >> 19;                              // 0:q 1:k
  unsigned int r = (idx >> 2) & 131071u;             // bh*2048 + s
  int quarter = idx & 3;
  int s = r & 2047;
  short* p = (part ? k : q) + ((size_t)r << 6) + quarter*16;
  s16x8 x0 = *(s16x8*)(p), x1 = *(s16x8*)(p + 8);
  const float* sr = sp + (size_t)s*64 + quarter*8;
  f32x4 sn0 = *(const f32x4*)(sr),      sn1 = *(const f32x4*)(sr + 4);
  f32x4 cs0 = *(const f32x4*)(sr + 32), cs1 = *(const f32x4*)(sr + 36);
  float scale = part ? 1.0f : 0.18033688011112042f;  // 1/sqrt(64) * log2(e)
  s16x8 y0, y1;
  #pragma unroll
  for (int j=0;j<4;j++){
    float e = bf2f(x0[2*j]), o = bf2f(x0[2*j+1]);
    y0[2*j]   = f2bf((e*cs0[j] - o*sn0[j])*scale);
    y0[2*j+1] = f2bf((o*cs0[j] + e*sn0[j])*scale);
    float e1 = bf2f(x1[2*j]), o1 = bf2f(x1[2*j+1]);
    y1[2*j]   = f2bf((e1*cs1[j] - o1*sn1[j])*scale);
    y1[2*j+1] = f2bf((o1*cs1[j] + e1*sn1[j])*scale);
  }
  *(s16x8*)(p) = y0; *(s16x8*)(p + 8) = y1;
}

// ---------------- V transpose: [bh][S][D] -> [bh][D][S] ----------------
__global__ __launch_bounds__(256) void vt_kernel(const short* __restrict__ v, short* __restrict__ vT){
  __shared__ short t[64*65];
  int s0 = blockIdx.x*64, bh = blockIdx.y;
  int tid = threadIdx.x;
  int srow = tid >> 2, cb = (tid & 3) * 16;
  const short* src = v + (((size_t)bh*Sd + s0 + srow) << 6) + cb;
  s16x8 a = *(const s16x8*)(src), b = *(const s16x8*)(src + 8);
  #pragma unroll
  for (int j=0;j<8;j++){ t[(cb+j)*65 + srow] = a[j]; t[(cb+8+j)*65 + srow] = b[j]; }
  __syncthreads();
  int d = tid >> 2, sb = (tid & 3) * 16;
  s16x8 o0, o1;
  #pragma unroll
  for (int j=0;j<8;j++){ o0[j] = t[d*65 + sb + j]; o1[j] = t[d*65 + sb + 8 + j]; }
  size_t obase = (((size_t)bh*Dd + d) << 11) + s0 + sb;
  *(s16x8*)(vT + obase)     = o0;
  *(s16x8*)(vT + obase + 8) = o1;
}

// ---------------- Flash attention: 4 waves/block, 16 q-rows/wave, KV tile 64 ----------------
__global__ __launch_bounds__(256) void attn_kernel(const short* __restrict__ q,
                                                   const short* __restrict__ k,
                                                   const short* __restrict__ vT,
                                                   float* __restrict__ out){
  __shared__ short plds[4][16*72];                   // per-wave P buffer, +8 pad
  int bid = blockIdx.x;
  int swz = (bid & 7) * 256 + (bid >> 3);            // XCD-chunked: same bh contiguous per XCD
  int bh = swz >> 5, qb = swz & 31;
  int tid = threadIdx.x, lane = tid & 63, wv = tid >> 6;
  int l15 = lane & 15, lq = lane >> 4;
  const short* qp = q  + (((size_t)bh*Sd + qb*64 + wv*16) << 6);
  const short* kp = k  + ((size_t)bh*Sd << 6);
  const short* vp = vT + ((size_t)bh*Dd << 11);
  short* pl = plds[wv];
  // Q a-frags (held whole loop): lane -> row l15, kdim 8*lq+i (+32)
  s16x8 qf0 = *(const s16x8*)(qp + l15*64 + 8*lq);
  s16x8 qf1 = *(const s16x8*)(qp + l15*64 + 32 + 8*lq);
  f32x4 zero = {0.f,0.f,0.f,0.f};
  f32x4 o[4]; 
  #pragma unroll
  for (int df=0;df<4;df++) o[df] = zero;
  float mr[4], lr[4];
  #pragma unroll
  for (int j=0;j<4;j++){ mr[j] = -1e30f; lr[j] = 0.f; }

  for (int kt = 0; kt < Sd; kt += 64){
    // S = Q K^T (already in log2 domain via q scale)
    f32x4 sf[4];
    #pragma unroll
    for (int kc=0;kc<4;kc++){
      const short* kr = kp + ((size_t)(kt + kc*16 + l15) << 6) + 8*lq;
      s16x8 kb0 = *(const s16x8*)(kr);
      s16x8 kb1 = *(const s16x8*)(kr + 32);
      f32x4 z = zero;
      z = __builtin_amdgcn_mfma_f32_16x16x32_bf16(qf0, kb0, z, 0, 0, 0);
      z = __builtin_amdgcn_mfma_f32_16x16x32_bf16(qf1, kb1, z, 0, 0, 0);
      sf[kc] = z;
    }
    // online softmax (C layout: row = lq*4+j, col = kc*16+l15)
    float al[4];
    #pragma unroll
    for (int j=0;j<4;j++){
      float tm = fmaxf(fmaxf(sf[0][j], sf[1][j]), fmaxf(sf[2][j], sf[3][j]));
      #pragma unroll
      for (int off=1;off<16;off<<=1) tm = fmaxf(tm, __shfl_xor(tm, off));
      float mn = fmaxf(mr[j], tm);
      al[j] = exp2f(mr[j] - mn);
      mr[j] = mn;
      float rs = 0.f;
      #pragma unroll
      for (int kc=0;kc<4;kc++){
        float pv = exp2f(sf[kc][j] - mn);
        sf[kc][j] = pv;
        rs += pv;
      }
      #pragma unroll
      for (int off=1;off<16;off<<=1) rs += __shfl_xor(rs, off);
      lr[j] = lr[j]*al[j] + rs;
    }
    #pragma unroll
    for (int df=0;df<4;df++)
      #pragma unroll
      for (int j=0;j<4;j++) o[df][j] *= al[j];
    // P -> LDS (bf16), re-read as A-frags (wave-private, no barrier needed)
    #pragma unroll
    for (int kc=0;kc<4;kc++)
      #pragma unroll
      for (int j=0;j<4;j++)
        pl[(lq*4+j)*72 + kc*16 + l15] = f2bf(sf[kc][j]);
    s16x8 pf0 = *(const s16x8*)(pl + l15*72 + 8*lq);
    s16x8 pf1 = *(const s16x8*)(pl + l15*72 + 32 + 8*lq);
    // O += P V  (B-frags from V^T: contiguous 16B per lane)
    #pragma unroll
    for (int df=0;df<4;df++){
      const short* vr = vp + ((size_t)(df*16 + l15) << 11) + kt + 8*lq;
      s16x8 vb0 = *(const s16x8*)(vr);
      s16x8 vb1 = *(const s16x8*)(vr + 32);
      o[df] = __builtin_amdgcn_mfma_f32_16x16x32_bf16(pf0, vb0, o[df], 0, 0, 0);
      o[df] = __builtin_amdgcn_mfma_f32_16x16x32_bf16(pf1, vb1, o[df], 0, 0, 0);
    }
  }
  // epilogue: out[b][s][h*64+d] = o / l
  int b = bh >> 4, hh = bh & 15;
  #pragma unroll
  for (int j=0;j<4;j++){
    float inv = 1.0f / lr[j];
    int srow = qb*64 + wv*16 + lq*4 + j;
    float* orow = out + (((size_t)(b*Sd + srow)) << 10) + hh*64;
    #pragma unroll
    for (int df=0;df<4;df++)
      orow[df*16 + l15] = o[df][j] * inv;
  }
}

extern "C" void kernel_launch(void* const* d_in, const int* in_sizes, int n_in,
                              void* d_out, int out_size, void* d_ws, size_t ws_size,
                              hipStream_t stream){
  const float* hs = (const float*)d_in[0];
  const float* sp = (const float*)d_in[1];
  const float* lw = (const float*)d_in[2];
  const float* lb = (const float*)d_in[3];
  const float* wq = (const float*)d_in[4];
  const float* bq = (const float*)d_in[5];
  float* out = (float*)d_out;
  char* ws = (char*)d_ws;
  // layout (bytes): [0,16.7M) h_bf16 (later reused for vT) | [16.7M,23.0M) wT | q | k | v
  short* h   = (short*)(ws);
  short* wT  = (short*)(ws + 16777216);
  short* vTb = (short*)(ws);                        // overlaps h: safe, h dead after GEMM
  short* qb_ = (short*)(ws + 23068672);
  short* kb_ = (short*)(ws + 23068672 + 16777216);
  short* vb_ = (short*)(ws + 23068672 + 33554432);  // total ws use: 73,400,320 B

  hipLaunchKernelGGL(ln_kernel,    dim3(8192),   dim3(256),   0, stream, hs, lw, lb, h);
  hipLaunchKernelGGL(castw_kernel, dim3(96,32),  dim3(32,8),  0, stream, wq, wT);
  hipLaunchKernelGGL(gemm_kernel,  dim3(1536),   dim3(256),   0, stream, h, wT, bq, qb_, kb_, vb_);
  hipLaunchKernelGGL(rope_kernel,  dim3(4096),   dim3(256),   0, stream, qb_, kb_, sp);
  hipLaunchKernelGGL(vt_kernel,    dim3(32,64),  dim3(256),   0, stream, vb_, vTb);
  hipLaunchKernelGGL(attn_kernel,  dim3(2048),   dim3(256),   0, stream, qb_, kb_, vTb, out);
}

// Round 3
// 194.020 us; speedup vs baseline: 2.8036x; 2.8036x over previous
//
#include <hip/hip_runtime.h>
#include <hip/hip_bf16.h>
#include <cstdint>
#include <cstddef>

#define DEVINL __device__ __forceinline__

typedef float f32x4 __attribute__((ext_vector_type(4)));
typedef float f32x16 __attribute__((ext_vector_type(16)));
typedef short s16x8 __attribute__((ext_vector_type(8)));
typedef short s16x4 __attribute__((ext_vector_type(4)));

static constexpr int Sd = 2048;   // sequence
static constexpr int Hd = 1024;   // hidden
static constexpr int NHd = 16;    // heads
static constexpr int Dd = 64;     // head dim
static constexpr int N3 = 3072;   // 3*H

DEVINL float bf2f(short u){
  unsigned int t = ((unsigned int)(unsigned short)u) << 16;
  float f; __builtin_memcpy(&f, &t, 4); return f;
}
DEVINL short f2bf(float f){
  unsigned int t; __builtin_memcpy(&t, &f, 4);
  unsigned int r = t + 0x7FFFu + ((t >> 16) & 1u);   // RNE
  return (short)(r >> 16);
}

DEVINL void gld16(const short* g, short* l){
  __builtin_amdgcn_global_load_lds((const __attribute__((address_space(1))) unsigned int*)g,
                                   (__attribute__((address_space(3))) unsigned int*)l, 16, 0, 0);
}

DEVINL int cvtpk(float lo, float hi){
  int r; asm("v_cvt_pk_bf16_f32 %0, %1, %2" : "=v"(r) : "v"(lo), "v"(hi)); return r;
}

DEVINL float fexp2(float x){
#if __has_builtin(__builtin_amdgcn_exp2f)
  return __builtin_amdgcn_exp2f(x);
#else
  return exp2f(x);
#endif
}

DEVINL f32x16 z16(){
  f32x16 v;
  #pragma unroll
  for (int i=0;i<16;i++) v[i]=0.f;
  return v;
}

// ---------------- LayerNorm + cast to bf16 ----------------
__global__ __launch_bounds__(256) void ln_kernel(const float* __restrict__ x,
                                                 const float* __restrict__ w,
                                                 const float* __restrict__ bs,
                                                 short* __restrict__ h){
  int row = blockIdx.x, tid = threadIdx.x;          // 8192 rows, 4 f32/thread
  const float* xr = x + (size_t)row * Hd;
  f32x4 v = *(const f32x4*)(xr + tid*4);
  float s1 = v[0]+v[1]+v[2]+v[3];
  float s2 = v[0]*v[0]+v[1]*v[1]+v[2]*v[2]+v[3]*v[3];
  #pragma unroll
  for (int off = 1; off < 64; off <<= 1){ s1 += __shfl_xor(s1, off); s2 += __shfl_xor(s2, off); }
  __shared__ float red[8];
  if ((tid & 63) == 0){ red[(tid>>6)*2] = s1; red[(tid>>6)*2+1] = s2; }
  __syncthreads();
  s1 = red[0]+red[2]+red[4]+red[6];
  s2 = red[1]+red[3]+red[5]+red[7];
  float mu = s1 * (1.0f/Hd);
  float rstd = rsqrtf(s2*(1.0f/Hd) - mu*mu + 1e-12f);
  f32x4 wv = *(const f32x4*)(w + tid*4);
  f32x4 bv = *(const f32x4*)(bs + tid*4);
  s16x4 o;
  #pragma unroll
  for (int i=0;i<4;i++) o[i] = f2bf((v[i]-mu)*rstd*wv[i] + bv[i]);
  *(s16x4*)(h + (size_t)row*Hd + tid*4) = o;
}

// ---------------- W cast + transpose: [K=1024][N=3072] f32 -> [N][K] bf16 ----------------
__global__ __launch_bounds__(256) void castw_kernel(const float* __restrict__ w, short* __restrict__ wT){
  __shared__ float t[32][33];
  int n0 = blockIdx.x*32, k0 = blockIdx.y*32;
  int tx = threadIdx.x, ty = threadIdx.y;           // (32,8)
  #pragma unroll
  for (int i=0;i<4;i++) t[ty + i*8][tx] = w[(size_t)(k0 + ty + i*8)*N3 + n0 + tx];
  __syncthreads();
  #pragma unroll
  for (int i=0;i<4;i++) wT[(size_t)(n0 + ty + i*8)*Hd + k0 + tx] = f2bf(t[tx][ty + i*8]);
}

// ---------------- QKV GEMM: C[8192][3072] = h @ w + b, write q/k/v bf16 head-layout ----------------
__global__ __launch_bounds__(256) void gemm_kernel(const short* __restrict__ A,
                                                   const short* __restrict__ Bt,
                                                   const float* __restrict__ bias,
                                                   short* __restrict__ qo,
                                                   short* __restrict__ ko,
                                                   short* __restrict__ vo){
  __shared__ short lA[128*32];
  __shared__ short lB[128*32];
  int bid = blockIdx.x;
  int xcd = bid & 7, idx = bid >> 3;                 // idx 0..191
  int mt = xcd*8 + (idx & 7), nt = idx >> 3;         // mt 0..63, nt 0..23
  int m0 = mt*128, n0 = nt*128;
  int tid = threadIdx.x, lane = tid & 63, wv = tid >> 6;
  int l15 = lane & 15, lq = lane >> 4;
  int wr = wv >> 1, wc = wv & 1;
  f32x4 zero = {0.f,0.f,0.f,0.f};
  f32x4 acc[4][4];
  #pragma unroll
  for (int m=0;m<4;m++)
    #pragma unroll
    for (int n=0;n<4;n++) acc[m][n] = zero;
  int flat = tid*8;
  int row0 = flat >> 5, col0 = flat & 31;
  const short* ga = A  + (size_t)(m0 + row0)*Hd + col0;
  const short* gb = Bt + (size_t)(n0 + row0)*Hd + col0;
  short* lAw = lA + wv*512;
  short* lBw = lB + wv*512;
  for (int kk = 0; kk < Hd; kk += 32){
    __syncthreads();
    gld16(ga + kk,                 lAw);
    gld16(ga + kk + (size_t)64*Hd, lAw + 2048);
    gld16(gb + kk,                 lBw);
    gld16(gb + kk + (size_t)64*Hd, lBw + 2048);
    __syncthreads();
    s16x8 af[4], bf[4];
    #pragma unroll
    for (int m=0;m<4;m++) af[m] = *(const s16x8*)(lA + (wr*64 + m*16 + l15)*32 + 8*lq);
    #pragma unroll
    for (int n=0;n<4;n++) bf[n] = *(const s16x8*)(lB + (wc*64 + n*16 + l15)*32 + 8*lq);
    #pragma unroll
    for (int m=0;m<4;m++)
      #pragma unroll
      for (int n=0;n<4;n++)
        acc[m][n] = __builtin_amdgcn_mfma_f32_16x16x32_bf16(af[m], bf[n], acc[m][n], 0, 0, 0);
  }
  #pragma unroll
  for (int n=0;n<4;n++){
    int c = n0 + wc*64 + n*16 + l15;
    float bv = bias[c];
    int part = c >> 10, hh = (c >> 6) & 15, d = c & 63;
    short* dst = part == 0 ? qo : (part == 1 ? ko : vo);
    #pragma unroll
    for (int m=0;m<4;m++){
      #pragma unroll
      for (int j=0;j<4;j++){
        int r = m0 + wr*64 + m*16 + lq*4 + j;       // global row = b*2048 + s
        int b = r >> 11, s = r & 2047;
        dst[(((size_t)((b*NHd + hh)*Sd + s)) << 6) + d] = f2bf(acc[m][n][j] + bv);
      }
    }
  }
}

// ---------------- RoPE in-place on q,k; folds 0.125*log2(e) into q ----------------
__global__ __launch_bounds__(256) void rope_kernel(short* __restrict__ q, short* __restrict__ k,
                                                   const float* __restrict__ sp){
  unsigned int idx = blockIdx.x*256 + threadIdx.x;  // 2^20 threads
  int part = idx >> 19;                              // 0:q 1:k
  unsigned int r = (idx >> 2) & 131071u;             // bh*2048 + s
  int quarter = idx & 3;
  int s = r & 2047;
  short* p = (part ? k : q) + ((size_t)r << 6) + quarter*16;
  s16x8 x0 = *(s16x8*)(p), x1 = *(s16x8*)(p + 8);
  const float* sr = sp + (size_t)s*64 + quarter*8;
  f32x4 sn0 = *(const f32x4*)(sr),      sn1 = *(const f32x4*)(sr + 4);
  f32x4 cs0 = *(const f32x4*)(sr + 32), cs1 = *(const f32x4*)(sr + 36);
  float scale = part ? 1.0f : 0.18033688011112042f;  // 1/sqrt(64) * log2(e)
  s16x8 y0, y1;
  #pragma unroll
  for (int j=0;j<4;j++){
    float e = bf2f(x0[2*j]), o = bf2f(x0[2*j+1]);
    y0[2*j]   = f2bf((e*cs0[j] - o*sn0[j])*scale);
    y0[2*j+1] = f2bf((o*cs0[j] + e*sn0[j])*scale);
    float e1 = bf2f(x1[2*j]), o1 = bf2f(x1[2*j+1]);
    y1[2*j]   = f2bf((e1*cs1[j] - o1*sn1[j])*scale);
    y1[2*j+1] = f2bf((o1*cs1[j] + e1*sn1[j])*scale);
  }
  *(s16x8*)(p) = y0; *(s16x8*)(p + 8) = y1;
}

// ---------------- V transpose: [bh][S][D] -> [bh][D][S] ----------------
__global__ __launch_bounds__(256) void vt_kernel(const short* __restrict__ v, short* __restrict__ vT){
  __shared__ short t[64*65];
  int s0 = blockIdx.x*64, bh = blockIdx.y;
  int tid = threadIdx.x;
  int srow = tid >> 2, cb = (tid & 3) * 16;
  const short* src = v + (((size_t)bh*Sd + s0 + srow) << 6) + cb;
  s16x8 a = *(const s16x8*)(src), b = *(const s16x8*)(src + 8);
  #pragma unroll
  for (int j=0;j<8;j++){ t[(cb+j)*65 + srow] = a[j]; t[(cb+8+j)*65 + srow] = b[j]; }
  __syncthreads();
  int d = tid >> 2, sb = (tid & 3) * 16;
  s16x8 o0, o1;
  #pragma unroll
  for (int j=0;j<8;j++){ o0[j] = t[d*65 + sb + j]; o1[j] = t[d*65 + sb + 8 + j]; }
  size_t obase = (((size_t)bh*Dd + d) << 11) + s0 + sb;
  *(s16x8*)(vT + obase)     = o0;
  *(s16x8*)(vT + obase + 8) = o1;
}

// ---------------- Flash attention: 8 waves x 32 q-rows, KV tile 64, swapped-operand ----------------
// S^T = mfma(K, Q): lane owns q = lane&31 (m, l, O^T all lane-local per q-row).
// K/V^T tiles staged to LDS via global_load_lds with chunk-XOR swizzle (c ^= row&7).
// P^T B-frag rebuild: from verified C-layout kv=(i&3)+8*(i>>2)+4*hi, receiving lane hi_l
// needs source-index base 8*(s4&1)+4*hi_l from BOTH half-lanes -> 2x shfl_xor(32) + selects.
__global__ __launch_bounds__(512, 4) void attn_kernel(const short* __restrict__ q,
                                                      const short* __restrict__ k,
                                                      const short* __restrict__ vT,
                                                      float* __restrict__ out){
  __shared__ alignas(16) short kbuf[2][4096];        // [64 kv][64 d], swizzled
  __shared__ alignas(16) short vbuf[2][4096];        // [64 d][64 kv], swizzled
  int bid = blockIdx.x;
  int xcd = bid & 7, w = bid >> 3;                   // same-bh blocks share an XCD's L2
  int bh = xcd*8 + (w >> 3), qb = w & 7;
  int tid = threadIdx.x, lane = tid & 63, wv = tid >> 6;
  int l31 = lane & 31, hi = lane >> 5;
  const short* kp = k  + ((size_t)bh << 17);
  const short* vp = vT + ((size_t)bh << 17);
  int qrow = qb*256 + wv*32 + l31;
  const short* qp = q + ((size_t)bh << 17) + (size_t)qrow*64;
  s16x8 qf[4];                                       // B-frag: col=q(lane&31), k = d = 16*kk+8*hi+i
  #pragma unroll
  for (int kk=0;kk<4;kk++) qf[kk] = *(const s16x8*)(qp + kk*16 + hi*8);

  // staging: 512 chunks of 16B per tile; thread c=tid stages chunk c with
  // inverse-swizzled source so swizzled reads land correctly (rule #21)
  int crow = tid >> 3;
  int scol = ((tid & 7) ^ (crow & 7)) * 8;
  const short* kg = kp + crow*64 + scol;             // += 4096/tile
  const short* vg = vp + (size_t)crow*2048 + scol;   // += 64/tile

  f32x16 ot0 = z16(), ot1 = z16();                   // O^T: col=q, row = d (db 0/1)
  float m = -1e30f, lr = 0.f;
  int rsw = (l31 & 7);                               // read-side row XOR (same for row, row+32)

  gld16(kg, &kbuf[0][0] + wv*512);
  gld16(vg, &vbuf[0][0] + wv*512);
  __syncthreads();

  for (int t = 0; t < 32; ++t){
    int cur = t & 1;
    if (t < 31){                                     // stage next tile (drained by barrier below)
      gld16(kg + (t+1)*4096, &kbuf[cur^1][0] + wv*512);
      gld16(vg + (t+1)*64,   &vbuf[cur^1][0] + wv*512);
    }
    const short* kb = &kbuf[cur][0];
    const short* vb = &vbuf[cur][0];
    // ---- S^T = K . Q^T  (two 32x32 tiles over kv, contraction d=64) ----
    f32x16 s0 = z16(), s1 = z16();
    #pragma unroll
    for (int kk=0;kk<4;kk++){
      s16x8 kf0 = *(const s16x8*)(kb + l31*64       + (((kk*2 + hi) ^ rsw)*8));
      s0 = __builtin_amdgcn_mfma_f32_32x32x16_bf16(kf0, qf[kk], s0, 0, 0, 0);
      s16x8 kf1 = *(const s16x8*)(kb + (32+l31)*64  + (((kk*2 + hi) ^ rsw)*8));
      s1 = __builtin_amdgcn_mfma_f32_32x32x16_bf16(kf1, qf[kk], s1, 0, 0, 0);
    }
    // ---- online softmax, lane-local per q-row (log2 domain) ----
    float tm[16];
    #pragma unroll
    for (int i=0;i<16;i++) tm[i] = fmaxf(s0[i], s1[i]);
    #pragma unroll
    for (int off=8; off>=1; off>>=1)
      #pragma unroll
      for (int i=0;i<off;i++) tm[i] = fmaxf(tm[i], tm[i+off]);
    float pmax = fmaxf(tm[0], __shfl_xor(tm[0], 32));
    if (!__all(pmax - m <= 8.0f)){                   // defer-max (T13)
      float mn = fmaxf(m, pmax);
      float al = fexp2(m - mn);
      m = mn; lr *= al;
      #pragma unroll
      for (int i=0;i<16;i++){ ot0[i] *= al; ot1[i] *= al; }
    }
    float rs = 0.f;
    #pragma unroll
    for (int i=0;i<16;i++){ s0[i] = fexp2(s0[i]-m); s1[i] = fexp2(s1[i]-m); }
    #pragma unroll
    for (int i=0;i<16;i++) rs += s0[i] + s1[i];
    lr += rs + __shfl_xor(rs, 32);
    // ---- P^T -> bf16 B-frags, O^T += V^T . P^T ----
    // B-frag dwords for group s4: dw0/dw1 from low half-lane, dw2/dw3 from high
    // half-lane, both at source index base 8*(s4&1) + 4*hi_l.
    #pragma unroll
    for (int s4=0;s4<4;s4++){
      int base = (s4 & 1) * 8;
      int pkA0, pkA1, pkB0, pkB1;
      if (s4 < 2){
        pkA0 = cvtpk(s0[base],   s0[base+1]); pkA1 = cvtpk(s0[base+2], s0[base+3]);
        pkB0 = cvtpk(s0[base+4], s0[base+5]); pkB1 = cvtpk(s0[base+6], s0[base+7]);
      } else {
        pkA0 = cvtpk(s1[base],   s1[base+1]); pkA1 = cvtpk(s1[base+2], s1[base+3]);
        pkB0 = cvtpk(s1[base+4], s1[base+5]); pkB1 = cvtpk(s1[base+6], s1[base+7]);
      }
      int r0 = __shfl_xor(hi ? pkA0 : pkB0, 32);     // hi=0 gets partner pkA0; hi=1 gets partner pkB0
      int r1 = __shfl_xor(hi ? pkA1 : pkB1, 32);
      union { int wq[4]; s16x8 v8; } u;
      u.wq[0] = hi ? r0   : pkA0;
      u.wq[1] = hi ? r1   : pkA1;
      u.wq[2] = hi ? pkB0 : r0;
      u.wq[3] = hi ? pkB1 : r1;
      s16x8 vf0 = *(const s16x8*)(vb + l31*64      + (((s4*2 + hi) ^ rsw)*8));
      ot0 = __builtin_amdgcn_mfma_f32_32x32x16_bf16(vf0, u.v8, ot0, 0, 0, 0);
      s16x8 vf1 = *(const s16x8*)(vb + (32+l31)*64 + (((s4*2 + hi) ^ rsw)*8));
      ot1 = __builtin_amdgcn_mfma_f32_32x32x16_bf16(vf1, u.v8, ot1, 0, 0, 0);
    }
    __syncthreads();                                 // drains vmcnt (stage) + all waves done with cur
  }
  // ---- epilogue: out[b][s=q][h*64 + d], d = 8g + 4hi + j (+32 for db=1) ----
  float inv = 1.0f / lr;
  int b = bh >> 4, hh = bh & 15;
  float* orow = out + ((size_t)(b*Sd + qrow) << 10) + hh*64;
  #pragma unroll
  for (int g=0; g<4; ++g){
    f32x4 w0, w1;
    #pragma unroll
    for (int j=0;j<4;j++){ w0[j] = ot0[4*g+j]*inv; w1[j] = ot1[4*g+j]*inv; }
    *(f32x4*)(orow + g*8 + 4*hi)      = w0;
    *(f32x4*)(orow + 32 + g*8 + 4*hi) = w1;
  }
}

extern "C" void kernel_launch(void* const* d_in, const int* in_sizes, int n_in,
                              void* d_out, int out_size, void* d_ws, size_t ws_size,
                              hipStream_t stream){
  const float* hs = (const float*)d_in[0];
  const float* sp = (const float*)d_in[1];
  const float* lw = (const float*)d_in[2];
  const float* lb = (const float*)d_in[3];
  const float* wq = (const float*)d_in[4];
  const float* bq = (const float*)d_in[5];
  float* out = (float*)d_out;
  char* ws = (char*)d_ws;
  short* h   = (short*)(ws);
  short* wT  = (short*)(ws + 16777216);
  short* vTb = (short*)(ws);                        // overlaps h: h dead after GEMM
  short* qb_ = (short*)(ws + 23068672);
  short* kb_ = (short*)(ws + 23068672 + 16777216);
  short* vb_ = (short*)(ws + 23068672 + 33554432);

  hipLaunchKernelGGL(ln_kernel,    dim3(8192),   dim3(256),   0, stream, hs, lw, lb, h);
  hipLaunchKernelGGL(castw_kernel, dim3(96,32),  dim3(32,8),  0, stream, wq, wT);
  hipLaunchKernelGGL(gemm_kernel,  dim3(1536),   dim3(256),   0, stream, h, wT, bq, qb_, kb_, vb_);
  hipLaunchKernelGGL(rope_kernel,  dim3(4096),   dim3(256),   0, stream, qb_, kb_, sp);
  hipLaunchKernelGGL(vt_kernel,    dim3(32,64),  dim3(256),   0, stream, vb_, vTb);
  hipLaunchKernelGGL(attn_kernel,  dim3(512),    dim3(512),   0, stream, qb_, kb_, vTb, out);
}

// Round 4
// 185.532 us; speedup vs baseline: 2.9318x; 1.0458x over previous
//
#include <hip/hip_runtime.h>
#include <hip/hip_bf16.h>
#include <cstdint>
#include <cstddef>

#define DEVINL __device__ __forceinline__

typedef float f32x4 __attribute__((ext_vector_type(4)));
typedef float f32x16 __attribute__((ext_vector_type(16)));
typedef short s16x8 __attribute__((ext_vector_type(8)));
typedef short s16x4 __attribute__((ext_vector_type(4)));

static constexpr int Sd = 2048;   // sequence
static constexpr int Hd = 1024;   // hidden
static constexpr int NHd = 16;    // heads
static constexpr int Dd = 64;     // head dim
static constexpr int N3 = 3072;   // 3*H

DEVINL float bf2f(short u){
  unsigned int t = ((unsigned int)(unsigned short)u) << 16;
  float f; __builtin_memcpy(&f, &t, 4); return f;
}
DEVINL short f2bf(float f){
  unsigned int t; __builtin_memcpy(&t, &f, 4);
  unsigned int r = t + 0x7FFFu + ((t >> 16) & 1u);   // RNE
  return (short)(r >> 16);
}

DEVINL void gld16(const short* g, short* l){
  __builtin_amdgcn_global_load_lds((const __attribute__((address_space(1))) unsigned int*)g,
                                   (__attribute__((address_space(3))) unsigned int*)l, 16, 0, 0);
}

DEVINL int cvtpk(float lo, float hi){
  int r; asm("v_cvt_pk_bf16_f32 %0, %1, %2" : "=v"(r) : "v"(lo), "v"(hi)); return r;
}

DEVINL float fexp2(float x){
#if __has_builtin(__builtin_amdgcn_exp2f)
  return __builtin_amdgcn_exp2f(x);
#else
  return exp2f(x);
#endif
}

DEVINL f32x16 z16(){
  f32x16 v;
  #pragma unroll
  for (int i=0;i<16;i++) v[i]=0.f;
  return v;
}

// ---------------- LayerNorm + cast to bf16 ----------------
__global__ __launch_bounds__(256) void ln_kernel(const float* __restrict__ x,
                                                 const float* __restrict__ w,
                                                 const float* __restrict__ bs,
                                                 short* __restrict__ h){
  int row = blockIdx.x, tid = threadIdx.x;          // 8192 rows, 4 f32/thread
  const float* xr = x + (size_t)row * Hd;
  f32x4 v = *(const f32x4*)(xr + tid*4);
  float s1 = v[0]+v[1]+v[2]+v[3];
  float s2 = v[0]*v[0]+v[1]*v[1]+v[2]*v[2]+v[3]*v[3];
  #pragma unroll
  for (int off = 1; off < 64; off <<= 1){ s1 += __shfl_xor(s1, off); s2 += __shfl_xor(s2, off); }
  __shared__ float red[8];
  if ((tid & 63) == 0){ red[(tid>>6)*2] = s1; red[(tid>>6)*2+1] = s2; }
  __syncthreads();
  s1 = red[0]+red[2]+red[4]+red[6];
  s2 = red[1]+red[3]+red[5]+red[7];
  float mu = s1 * (1.0f/Hd);
  float rstd = rsqrtf(s2*(1.0f/Hd) - mu*mu + 1e-12f);
  f32x4 wv = *(const f32x4*)(w + tid*4);
  f32x4 bv = *(const f32x4*)(bs + tid*4);
  s16x4 o;
  #pragma unroll
  for (int i=0;i<4;i++) o[i] = f2bf((v[i]-mu)*rstd*wv[i] + bv[i]);
  *(s16x4*)(h + (size_t)row*Hd + tid*4) = o;
}

// ---------------- W cast + transpose: [K=1024][N=3072] f32 -> [N][K] bf16 ----------------
__global__ __launch_bounds__(256) void castw_kernel(const float* __restrict__ w, short* __restrict__ wT){
  __shared__ float t[32][33];
  int n0 = blockIdx.x*32, k0 = blockIdx.y*32;
  int tx = threadIdx.x, ty = threadIdx.y;           // (32,8)
  #pragma unroll
  for (int i=0;i<4;i++) t[ty + i*8][tx] = w[(size_t)(k0 + ty + i*8)*N3 + n0 + tx];
  __syncthreads();
  #pragma unroll
  for (int i=0;i<4;i++) wT[(size_t)(n0 + ty + i*8)*Hd + k0 + tx] = f2bf(t[tx][ty + i*8]);
}

// ---------------- QKV GEMM: C[8192][3072] = h @ w + b, write q/k/v bf16 head-layout ----------------
__global__ __launch_bounds__(256) void gemm_kernel(const short* __restrict__ A,
                                                   const short* __restrict__ Bt,
                                                   const float* __restrict__ bias,
                                                   short* __restrict__ qo,
                                                   short* __restrict__ ko,
                                                   short* __restrict__ vo){
  __shared__ short lA[128*32];
  __shared__ short lB[128*32];
  int bid = blockIdx.x;
  int xcd = bid & 7, idx = bid >> 3;                 // idx 0..191
  int mt = xcd*8 + (idx & 7), nt = idx >> 3;         // mt 0..63, nt 0..23
  int m0 = mt*128, n0 = nt*128;
  int tid = threadIdx.x, lane = tid & 63, wv = tid >> 6;
  int l15 = lane & 15, lq = lane >> 4;
  int wr = wv >> 1, wc = wv & 1;
  f32x4 zero = {0.f,0.f,0.f,0.f};
  f32x4 acc[4][4];
  #pragma unroll
  for (int m=0;m<4;m++)
    #pragma unroll
    for (int n=0;n<4;n++) acc[m][n] = zero;
  int flat = tid*8;
  int row0 = flat >> 5, col0 = flat & 31;
  const short* ga = A  + (size_t)(m0 + row0)*Hd + col0;
  const short* gb = Bt + (size_t)(n0 + row0)*Hd + col0;
  short* lAw = lA + wv*512;
  short* lBw = lB + wv*512;
  for (int kk = 0; kk < Hd; kk += 32){
    __syncthreads();
    gld16(ga + kk,                 lAw);
    gld16(ga + kk + (size_t)64*Hd, lAw + 2048);
    gld16(gb + kk,                 lBw);
    gld16(gb + kk + (size_t)64*Hd, lBw + 2048);
    __syncthreads();
    s16x8 af[4], bf[4];
    #pragma unroll
    for (int m=0;m<4;m++) af[m] = *(const s16x8*)(lA + (wr*64 + m*16 + l15)*32 + 8*lq);
    #pragma unroll
    for (int n=0;n<4;n++) bf[n] = *(const s16x8*)(lB + (wc*64 + n*16 + l15)*32 + 8*lq);
    #pragma unroll
    for (int m=0;m<4;m++)
      #pragma unroll
      for (int n=0;n<4;n++)
        acc[m][n] = __builtin_amdgcn_mfma_f32_16x16x32_bf16(af[m], bf[n], acc[m][n], 0, 0, 0);
  }
  #pragma unroll
  for (int n=0;n<4;n++){
    int c = n0 + wc*64 + n*16 + l15;
    float bv = bias[c];
    int part = c >> 10, hh = (c >> 6) & 15, d = c & 63;
    short* dst = part == 0 ? qo : (part == 1 ? ko : vo);
    #pragma unroll
    for (int m=0;m<4;m++){
      #pragma unroll
      for (int j=0;j<4;j++){
        int r = m0 + wr*64 + m*16 + lq*4 + j;       // global row = b*2048 + s
        int b = r >> 11, s = r & 2047;
        dst[(((size_t)((b*NHd + hh)*Sd + s)) << 6) + d] = f2bf(acc[m][n][j] + bv);
      }
    }
  }
}

// ---------------- prep: y=0 -> RoPE on K (in-place); y=1 -> V transpose ----------------
__global__ __launch_bounds__(256) void prep_kernel(short* __restrict__ k,
                                                   const short* __restrict__ v,
                                                   short* __restrict__ vT,
                                                   const float* __restrict__ sp){
  if (blockIdx.y == 0){
    unsigned int idx = blockIdx.x*256 + threadIdx.x;  // 2^19 threads over k
    unsigned int r = idx >> 2;                        // bh*2048 + s
    int quarter = idx & 3;
    int s = r & 2047;
    short* p = k + ((size_t)r << 6) + quarter*16;
    s16x8 x0 = *(s16x8*)(p), x1 = *(s16x8*)(p + 8);
    const float* sr = sp + (size_t)s*64 + quarter*8;
    f32x4 sn0 = *(const f32x4*)(sr),      sn1 = *(const f32x4*)(sr + 4);
    f32x4 cs0 = *(const f32x4*)(sr + 32), cs1 = *(const f32x4*)(sr + 36);
    s16x8 y0, y1;
    #pragma unroll
    for (int j=0;j<4;j++){
      float e = bf2f(x0[2*j]), o = bf2f(x0[2*j+1]);
      y0[2*j]   = f2bf(e*cs0[j] - o*sn0[j]);
      y0[2*j+1] = f2bf(o*cs0[j] + e*sn0[j]);
      float e1 = bf2f(x1[2*j]), o1 = bf2f(x1[2*j+1]);
      y1[2*j]   = f2bf(e1*cs1[j] - o1*sn1[j]);
      y1[2*j+1] = f2bf(o1*cs1[j] + e1*sn1[j]);
    }
    *(s16x8*)(p) = y0; *(s16x8*)(p + 8) = y1;
  } else {
    __shared__ short t[64*65];
    int s0 = (blockIdx.x & 31)*64, bh = blockIdx.x >> 5;
    int tid = threadIdx.x;
    int srow = tid >> 2, cb = (tid & 3) * 16;
    const short* src = v + (((size_t)bh*Sd + s0 + srow) << 6) + cb;
    s16x8 a = *(const s16x8*)(src), b = *(const s16x8*)(src + 8);
    #pragma unroll
    for (int j=0;j<8;j++){ t[(cb+j)*65 + srow] = a[j]; t[(cb+8+j)*65 + srow] = b[j]; }
    __syncthreads();
    int d = tid >> 2, sb = (tid & 3) * 16;
    s16x8 o0, o1;
    #pragma unroll
    for (int j=0;j<8;j++){ o0[j] = t[d*65 + sb + j]; o1[j] = t[d*65 + sb + 8 + j]; }
    size_t obase = (((size_t)bh*Dd + d) << 11) + s0 + sb;
    *(s16x8*)(vT + obase)     = o0;
    *(s16x8*)(vT + obase + 8) = o1;
  }
}

// ---------------- Flash attention: 8 waves x 32 q-rows, KV stage 128 (2x64 halves) ----------------
// S^T = mfma(K, Q): lane owns q = lane&31. Q-RoPE applied in-kernel (lane owns one q-row).
// K [128][64] and V^T [64][128] staged via global_load_lds, chunk-XOR swizzle on low 3 bits
// (both-sides, rule #21). One barrier per 128 kv. Softmax sums tree-reduced.
__global__ __launch_bounds__(512, 4) void attn_kernel(const short* __restrict__ q,
                                                      const short* __restrict__ k,
                                                      const short* __restrict__ vT,
                                                      const float* __restrict__ sp,
                                                      float* __restrict__ out){
  __shared__ alignas(16) short kbuf[2][8192];        // [128 kv][64 d], swizzled (32 KB)
  __shared__ alignas(16) short vbuf[2][8192];        // [64 d][128 kv], swizzled (32 KB)
  int bid = blockIdx.x;
  int xcd = bid & 7, w = bid >> 3;                   // same-bh blocks share an XCD's L2
  int bh = xcd*8 + (w >> 3), qb = w & 7;
  int tid = threadIdx.x, lane = tid & 63, wv = tid >> 6;
  int l31 = lane & 31, hi = lane >> 5;
  const short* kp = k  + ((size_t)bh << 17);
  const short* vp = vT + ((size_t)bh << 17);
  int qrow = qb*256 + wv*32 + l31;
  const short* qp = q + ((size_t)bh << 17) + (size_t)qrow*64;
  // ---- Q load + RoPE (pairs are adjacent within each 8-vector; lane owns row qrow) ----
  const float* spq = sp + (size_t)qrow*64;
  const float qs = 0.18033688011112042f;             // 1/sqrt(64) * log2(e)
  s16x8 qf[4];                                       // B-frag: col=q(lane&31), k = d = 16*kk+8*hi+i
  #pragma unroll
  for (int kk=0;kk<4;kk++){
    s16x8 x = *(const s16x8*)(qp + kk*16 + hi*8);
    f32x4 sn = *(const f32x4*)(spq + kk*8 + hi*4);
    f32x4 cs = *(const f32x4*)(spq + 32 + kk*8 + hi*4);
    s16x8 y;
    #pragma unroll
    for (int j=0;j<4;j++){
      float e = bf2f(x[2*j]), o = bf2f(x[2*j+1]);
      y[2*j]   = f2bf((e*cs[j] - o*sn[j])*qs);
      y[2*j+1] = f2bf((o*cs[j] + e*sn[j])*qs);
    }
    qf[kk] = y;
  }
  // ---- staging offsets (inverse-swizzled global source; LDS linear dest = tid*8 shorts/round) ----
  int kc0 = tid,      kr0 = kc0 >> 3;
  int kc1 = tid+512,  kr1 = kc1 >> 3;
  int koff0 = kr0*64 + ((kc0 ^ kr0) & 7)*8;
  int koff1 = kr1*64 + ((kc1 ^ kr1) & 7)*8;
  int vr0 = tid >> 4,       vcc0 = tid & 15;
  int vr1 = (tid+512) >> 4, vcc1 = (tid+512) & 15;
  int voff0 = vr0*2048 + ((vcc0 & 8) | ((vcc0 ^ vr0) & 7))*8;
  int voff1 = vr1*2048 + ((vcc1 & 8) | ((vcc1 ^ vr1) & 7))*8;

  f32x16 ot0 = z16(), ot1 = z16();                   // O^T: col=q, row = d
  float m = -1e30f, lr = 0.f;
  int rsw = (l31 & 7);                               // read-side chunk XOR

#define STAGE(nb, t) do { \
    gld16(kp + (size_t)(t)*8192 + koff0, &kbuf[nb][0]    + wv*512); \
    gld16(kp + (size_t)(t)*8192 + koff1, &kbuf[nb][4096] + wv*512); \
    gld16(vp + (size_t)(t)*128  + voff0, &vbuf[nb][0]    + wv*512); \
    gld16(vp + (size_t)(t)*128  + voff1, &vbuf[nb][4096] + wv*512); \
  } while(0)

  STAGE(0, 0);
  __syncthreads();

  for (int t = 0; t < 16; ++t){
    int cur = t & 1;
    if (t < 15) STAGE(cur^1, t+1);                   // drained by barrier at end of t
    #pragma unroll
    for (int h = 0; h < 2; ++h){
      const short* kb = &kbuf[cur][h*4096];
      const short* vb = &vbuf[cur][h*64];
      // ---- S^T = K . Q^T  (two 32x32 kv tiles, contraction d=64) ----
      f32x16 s0 = z16(), s1 = z16();
      __builtin_amdgcn_s_setprio(1);
      #pragma unroll
      for (int kk=0;kk<4;kk++){
        s16x8 kf0 = *(const s16x8*)(kb + l31*64       + (((kk*2 + hi) ^ rsw)*8));
        s0 = __builtin_amdgcn_mfma_f32_32x32x16_bf16(kf0, qf[kk], s0, 0, 0, 0);
        s16x8 kf1 = *(const s16x8*)(kb + (32+l31)*64  + (((kk*2 + hi) ^ rsw)*8));
        s1 = __builtin_amdgcn_mfma_f32_32x32x16_bf16(kf1, qf[kk], s1, 0, 0, 0);
      }
      __builtin_amdgcn_s_setprio(0);
      // ---- online softmax, lane-local per q-row (log2 domain) ----
      float tm[16];
      #pragma unroll
      for (int i=0;i<16;i++) tm[i] = fmaxf(s0[i], s1[i]);
      #pragma unroll
      for (int off=8; off>=1; off>>=1)
        #pragma unroll
        for (int i=0;i<off;i++) tm[i] = fmaxf(tm[i], tm[i+off]);
      float pmax = fmaxf(tm[0], __shfl_xor(tm[0], 32));
      if (!__all(pmax - m <= 8.0f)){                 // defer-max (T13)
        float mn = fmaxf(m, pmax);
        float al = fexp2(m - mn);
        m = mn; lr *= al;
        #pragma unroll
        for (int i=0;i<16;i++){ ot0[i] *= al; ot1[i] *= al; }
      }
      #pragma unroll
      for (int i=0;i<16;i++){ s0[i] = fexp2(s0[i]-m); s1[i] = fexp2(s1[i]-m); }
      float ra[16];
      #pragma unroll
      for (int i=0;i<16;i++) ra[i] = s0[i] + s1[i];
      #pragma unroll
      for (int off=8; off>=1; off>>=1)
        #pragma unroll
        for (int i=0;i<off;i++) ra[i] += ra[i+off];
      lr += ra[0] + __shfl_xor(ra[0], 32);
      // ---- P^T -> bf16 B-frags, O^T += V^T . P^T ----
      #pragma unroll
      for (int s4=0;s4<4;s4++){
        int base = (s4 & 1) * 8;
        int pkA0, pkA1, pkB0, pkB1;
        if (s4 < 2){
          pkA0 = cvtpk(s0[base],   s0[base+1]); pkA1 = cvtpk(s0[base+2], s0[base+3]);
          pkB0 = cvtpk(s0[base+4], s0[base+5]); pkB1 = cvtpk(s0[base+6], s0[base+7]);
        } else {
          pkA0 = cvtpk(s1[base],   s1[base+1]); pkA1 = cvtpk(s1[base+2], s1[base+3]);
          pkB0 = cvtpk(s1[base+4], s1[base+5]); pkB1 = cvtpk(s1[base+6], s1[base+7]);
        }
        int r0 = __shfl_xor(hi ? pkA0 : pkB0, 32);
        int r1 = __shfl_xor(hi ? pkA1 : pkB1, 32);
        union { int wq[4]; s16x8 v8; } u;
        u.wq[0] = hi ? r0   : pkA0;
        u.wq[1] = hi ? r1   : pkA1;
        u.wq[2] = hi ? pkB0 : r0;
        u.wq[3] = hi ? pkB1 : r1;
        __builtin_amdgcn_s_setprio(1);
        s16x8 vf0 = *(const s16x8*)(vb + l31*128      + (((s4*2 + hi) ^ rsw)*8));
        ot0 = __builtin_amdgcn_mfma_f32_32x32x16_bf16(vf0, u.v8, ot0, 0, 0, 0);
        s16x8 vf1 = *(const s16x8*)(vb + (32+l31)*128 + (((s4*2 + hi) ^ rsw)*8));
        ot1 = __builtin_amdgcn_mfma_f32_32x32x16_bf16(vf1, u.v8, ot1, 0, 0, 0);
        __builtin_amdgcn_s_setprio(0);
      }
    }
    __syncthreads();                                 // drains vmcnt (stage) + all waves done with cur
  }
#undef STAGE
  // ---- epilogue: out[b][s=q][h*64 + d], d = 8g + 4hi + j (+32 for db=1) ----
  float inv = 1.0f / lr;
  int b = bh >> 4, hh = bh & 15;
  float* orow = out + ((size_t)(b*Sd + qrow) << 10) + hh*64;
  #pragma unroll
  for (int g=0; g<4; ++g){
    f32x4 w0, w1;
    #pragma unroll
    for (int j=0;j<4;j++){ w0[j] = ot0[4*g+j]*inv; w1[j] = ot1[4*g+j]*inv; }
    *(f32x4*)(orow + g*8 + 4*hi)      = w0;
    *(f32x4*)(orow + 32 + g*8 + 4*hi) = w1;
  }
}

extern "C" void kernel_launch(void* const* d_in, const int* in_sizes, int n_in,
                              void* d_out, int out_size, void* d_ws, size_t ws_size,
                              hipStream_t stream){
  const float* hs = (const float*)d_in[0];
  const float* sp = (const float*)d_in[1];
  const float* lw = (const float*)d_in[2];
  const float* lb = (const float*)d_in[3];
  const float* wq = (const float*)d_in[4];
  const float* bq = (const float*)d_in[5];
  float* out = (float*)d_out;
  char* ws = (char*)d_ws;
  short* h   = (short*)(ws);
  short* wT  = (short*)(ws + 16777216);
  short* vTb = (short*)(ws);                        // overlaps h: h dead after GEMM
  short* qb_ = (short*)(ws + 23068672);
  short* kb_ = (short*)(ws + 23068672 + 16777216);
  short* vb_ = (short*)(ws + 23068672 + 33554432);

  hipLaunchKernelGGL(ln_kernel,    dim3(8192),    dim3(256),   0, stream, hs, lw, lb, h);
  hipLaunchKernelGGL(castw_kernel, dim3(96,32),   dim3(32,8),  0, stream, wq, wT);
  hipLaunchKernelGGL(gemm_kernel,  dim3(1536),    dim3(256),   0, stream, h, wT, bq, qb_, kb_, vb_);
  hipLaunchKernelGGL(prep_kernel,  dim3(2048,2),  dim3(256),   0, stream, kb_, vb_, vTb, sp);
  hipLaunchKernelGGL(attn_kernel,  dim3(512),     dim3(512),   0, stream, qb_, kb_, vTb, sp, out);
}